// Round 11
// baseline (329.204 us; speedup 1.0000x reference)
//
#include <hip/hip_runtime.h>

// Problem constants (match reference setup_inputs)
#define NODES 50000
#define NEDGE 1600000
#define ND 64      // NODE_DIM
#define ED 32      // EDGE_DIM
#define HID 64     // HIDDEN
#define IN_DIM 96  // ND + ED

#define TW2 32       // edges per wave-private micro-tile (2 row-groups of 16)
#define H_LD   72    // bf16/row: 64 data + 8 pad -> 144 B rows; pad bytes 128..143 hold pd rec
#define W1_LD  104   // w1T row stride (bf16): [cn][k] rows 208 B
#define W2_LD  72    // w2T row stride (bf16): 144 B

typedef __bf16 bf16_t;
typedef __bf16 bf16x8_t __attribute__((ext_vector_type(8)));
typedef float  f32x4_t  __attribute__((ext_vector_type(4)));

#define SCAN_B 256
#define SCAN_NBLK ((NODES + SCAN_B - 1) / SCAN_B)   // 196

#define NXCD 8
#define NODES_PER_G ((NODES + NXCD - 1) / NXCD)   // 6250

// ---------------- K0: zero out accumulator + counts ----------------
__global__ void zero_kernel(float* __restrict__ out, int* __restrict__ cnt) {
    int i = blockIdx.x * blockDim.x + threadIdx.x;
    int stride = gridDim.x * blockDim.x;
    const int total = NODES * ND;
    for (int idx = i; idx < total; idx += stride) out[idx] = 0.0f;
    for (int idx = i; idx < NODES; idx += stride) cnt[idx] = 0;
}

// ---------------- K1: histogram of dst ----------------
__global__ void hist_kernel(const int* __restrict__ ei, int* __restrict__ cnt) {
    int i = blockIdx.x * blockDim.x + threadIdx.x;
    int stride = gridDim.x * blockDim.x;
    for (int e = i; e < NEDGE; e += stride)
        atomicAdd(&cnt[ei[NEDGE + e]], 1);
}

// ---------------- K2a: per-block partial sums of cnt ----------------
__global__ void scan_sum_kernel(const int* __restrict__ cnt, int* __restrict__ bsum) {
    __shared__ int sh[SCAN_B];
    const int t = threadIdx.x, b = blockIdx.x;
    const int i = b * SCAN_B + t;
    sh[t] = (i < NODES) ? cnt[i] : 0;
    __syncthreads();
    for (int d = SCAN_B / 2; d > 0; d >>= 1) {
        if (t < d) sh[t] += sh[t + d];
        __syncthreads();
    }
    if (t == 0) bsum[b] = sh[0];
}

// ---------------- K2b: exclusive scan of 196 block sums (1 tiny block) ----------------
__global__ void scan_top_kernel(int* __restrict__ bsum) {
    __shared__ int sh[SCAN_B];
    const int t = threadIdx.x;
    sh[t] = (t < SCAN_NBLK) ? bsum[t] : 0;
    __syncthreads();
    for (int d = 1; d < SCAN_B; d <<= 1) {
        int v = (t >= d) ? sh[t - d] : 0;
        __syncthreads();
        sh[t] += v;
        __syncthreads();
    }
    if (t < SCAN_NBLK) bsum[t] = (t == 0) ? 0 : sh[t - 1];   // exclusive
}

// ---------------- K2c: fill cursor = global exclusive prefix of cnt ----------------
__global__ void scan_fill_kernel(const int* __restrict__ cnt, const int* __restrict__ bsum,
                                 int* __restrict__ cursor) {
    __shared__ int sh[SCAN_B];
    const int t = threadIdx.x, b = blockIdx.x;
    const int i = b * SCAN_B + t;
    int v = (i < NODES) ? cnt[i] : 0;
    sh[t] = v;
    __syncthreads();
    for (int d = 1; d < SCAN_B; d <<= 1) {
        int u = (t >= d) ? sh[t - d] : 0;
        __syncthreads();
        sh[t] += u;
        __syncthreads();
    }
    if (i < NODES) cursor[i] = bsum[b] + sh[t] - v;   // exclusive
}

// ---------------- K3: bucket-scatter, XCD-partitioned by dst range ----------------
__global__ void bucket_kernel(const int* __restrict__ ei, int* __restrict__ cursor,
                              int2* __restrict__ pd) {
    const int g   = blockIdx.x & (NXCD - 1);
    const int bg  = blockIdx.x >> 3;            // block index within group
    const int bpg = gridDim.x >> 3;             // blocks per group
    const int lo  = g * NODES_PER_G;
    const int hi  = min(lo + NODES_PER_G, NODES);
    int i = bg * blockDim.x + threadIdx.x;
    int stride = bpg * blockDim.x;
    for (int e = i; e < NEDGE; e += stride) {
        int d = ei[NEDGE + e];
        if (d >= lo && d < hi) {
            int pos = atomicAdd(&cursor[d], 1);
            pd[pos] = make_int2(e, d);
        }
    }
}

static __device__ __forceinline__ bf16x8_t cvt8(float4 a, float4 b) {
    bf16x8_t f;
    f[0] = (bf16_t)a.x; f[1] = (bf16_t)a.y; f[2] = (bf16_t)a.z; f[3] = (bf16_t)a.w;
    f[4] = (bf16_t)b.x; f[5] = (bf16_t)b.y; f[6] = (bf16_t)b.z; f[7] = (bf16_t)b.w;
    return f;
}

// ---------------- K4: per-edge MLP via bf16 MFMA — direct-global A-frags, TW=32 ----------------
// Each wave owns a 32-edge micro-tile (2 row-groups of 16). A-fragments for GEMM1
// are loaded straight from global (x + edge_attr) into registers, converted to
// bf16 in-register -> the msg LDS round-trip is gone. h and m go through the
// wave-private hS [32][72] buffer; pd records live in its 16B row pad.
// One block barrier total (after weight staging).
__global__ __launch_bounds__(256, 4)
void edge_mlp_mfma(const float* __restrict__ x,
                   const float* __restrict__ edge_attr,
                   const float* __restrict__ W1, const float* __restrict__ b1,
                   const float* __restrict__ W2, const float* __restrict__ b2,
                   const int2* __restrict__ pd,
                   float* __restrict__ out_sum)
{
    __shared__ __align__(16) bf16_t w1T[HID * W1_LD];        // 13312 B
    __shared__ __align__(16) bf16_t w2T[ND * W2_LD];         //  9216 B
    __shared__ __align__(16) bf16_t hS_all[4 * TW2 * H_LD];  // 18432 B  (total 40960 = 40KB)

    const int t    = threadIdx.x;
    const int lane = t & 63;
    const int w    = t >> 6;         // wave id 0..3
    const int col  = lane & 15;      // MFMA col / A-row selector
    const int kq   = lane >> 4;      // 0..3: k-quarter

    bf16_t* hS = hS_all + w * TW2 * H_LD;   // [32][H_LD]; cols 64..71 = pd pad

    // ---- one-time: transpose W1,W2 into LDS (bf16) ----
    for (int i = t; i < IN_DIM * HID / 4; i += 256) {
        float4 v = ((const float4*)W1)[i];
        int k = i >> 4, j4 = (i & 15) * 4;      // W1[k][j4..j4+3]
        w1T[(j4 + 0) * W1_LD + k] = (bf16_t)v.x;
        w1T[(j4 + 1) * W1_LD + k] = (bf16_t)v.y;
        w1T[(j4 + 2) * W1_LD + k] = (bf16_t)v.z;
        w1T[(j4 + 3) * W1_LD + k] = (bf16_t)v.w;
    }
    for (int i = t; i < HID * ND / 4; i += 256) {
        float4 v = ((const float4*)W2)[i];
        int k = i >> 4, j4 = (i & 15) * 4;
        w2T[(j4 + 0) * W2_LD + k] = (bf16_t)v.x;
        w2T[(j4 + 1) * W2_LD + k] = (bf16_t)v.y;
        w2T[(j4 + 2) * W2_LD + k] = (bf16_t)v.z;
        w2T[(j4 + 3) * W2_LD + k] = (bf16_t)v.w;
    }
    float b1r[4], b2r[4];
    #pragma unroll
    for (int nt = 0; nt < 4; ++nt) {
        b1r[nt] = b1[col + 16 * nt];
        b2r[nt] = b2[col + 16 * nt];
    }
    __syncthreads();   // the only block barrier

    const int ntiles = NEDGE / TW2;              // 50000
    const int wid = blockIdx.x * 4 + w;
    const int nw  = gridDim.x * 4;

    for (int tile = wid; tile < ntiles; tile += nw) {
        const int eb = tile * TW2;

        // park pd records in the hS row pad (prev scatter reads already issued; in-order DS pipe)
        if (lane < TW2) *(int2*)&hS[lane * H_LD + 64] = pd[eb + lane];

        // ---- A-fragments straight from global, per row-group ----
        bf16x8_t a0[3], a1[3];
        {
            int2 rec = *(const int2*)&hS[col * H_LD + 64];
            const float4* xr = (const float4*)(x + (size_t)rec.y * ND);
            const float4* er = (const float4*)(edge_attr + (size_t)rec.x * ED);
            a0[0] = cvt8(xr[2 * kq],     xr[2 * kq + 1]);
            a0[1] = cvt8(xr[8 + 2 * kq], xr[8 + 2 * kq + 1]);
            a0[2] = cvt8(er[2 * kq],     er[2 * kq + 1]);
        }
        {
            int2 rec = *(const int2*)&hS[(16 + col) * H_LD + 64];
            const float4* xr = (const float4*)(x + (size_t)rec.y * ND);
            const float4* er = (const float4*)(edge_attr + (size_t)rec.x * ED);
            a1[0] = cvt8(xr[2 * kq],     xr[2 * kq + 1]);
            a1[1] = cvt8(xr[8 + 2 * kq], xr[8 + 2 * kq + 1]);
            a1[2] = cvt8(er[2 * kq],     er[2 * kq + 1]);
        }

        // ---- GEMM1: h = relu(msg @ W1 + b1), both row-groups share weight frags ----
        f32x4_t acc0[4], acc1[4];
        #pragma unroll
        for (int nt = 0; nt < 4; ++nt) {
            const bf16_t* wr = &w1T[(col + 16 * nt) * W1_LD + kq * 8];
            bf16x8_t f0 = *(const bf16x8_t*)(wr + 0 * 32);
            bf16x8_t f1 = *(const bf16x8_t*)(wr + 1 * 32);
            bf16x8_t f2 = *(const bf16x8_t*)(wr + 2 * 32);
            acc0[nt] = (f32x4_t){0.0f, 0.0f, 0.0f, 0.0f};
            acc1[nt] = (f32x4_t){0.0f, 0.0f, 0.0f, 0.0f};
            acc0[nt] = __builtin_amdgcn_mfma_f32_16x16x32_bf16(a0[0], f0, acc0[nt], 0, 0, 0);
            acc1[nt] = __builtin_amdgcn_mfma_f32_16x16x32_bf16(a1[0], f0, acc1[nt], 0, 0, 0);
            acc0[nt] = __builtin_amdgcn_mfma_f32_16x16x32_bf16(a0[1], f1, acc0[nt], 0, 0, 0);
            acc1[nt] = __builtin_amdgcn_mfma_f32_16x16x32_bf16(a1[1], f1, acc1[nt], 0, 0, 0);
            acc0[nt] = __builtin_amdgcn_mfma_f32_16x16x32_bf16(a0[2], f2, acc0[nt], 0, 0, 0);
            acc1[nt] = __builtin_amdgcn_mfma_f32_16x16x32_bf16(a1[2], f2, acc1[nt], 0, 0, 0);
        }
        // epilogue: bias+relu -> hS rows (C/D: row = 16*rg + 4*kq + r, col = col+16*nt)
        #pragma unroll
        for (int nt = 0; nt < 4; ++nt)
            #pragma unroll
            for (int r = 0; r < 4; ++r) {
                hS[(4 * kq + r) * H_LD + col + 16 * nt]        = (bf16_t)fmaxf(acc0[nt][r] + b1r[nt], 0.0f);
                hS[(16 + 4 * kq + r) * H_LD + col + 16 * nt]   = (bf16_t)fmaxf(acc1[nt][r] + b1r[nt], 0.0f);
            }

        // ---- GEMM2: m = relu(h @ W2 + b2); m overwrites h rows in place ----
        bf16x8_t ah0[2], ah1[2];
        ah0[0] = *(const bf16x8_t*)&hS[col * H_LD + 0 * 32 + kq * 8];
        ah0[1] = *(const bf16x8_t*)&hS[col * H_LD + 1 * 32 + kq * 8];
        ah1[0] = *(const bf16x8_t*)&hS[(16 + col) * H_LD + 0 * 32 + kq * 8];
        ah1[1] = *(const bf16x8_t*)&hS[(16 + col) * H_LD + 1 * 32 + kq * 8];
        f32x4_t ac20[4], ac21[4];
        #pragma unroll
        for (int nt = 0; nt < 4; ++nt) {
            const bf16_t* wr = &w2T[(col + 16 * nt) * W2_LD + kq * 8];
            bf16x8_t f0 = *(const bf16x8_t*)(wr + 0 * 32);
            bf16x8_t f1 = *(const bf16x8_t*)(wr + 1 * 32);
            ac20[nt] = (f32x4_t){0.0f, 0.0f, 0.0f, 0.0f};
            ac21[nt] = (f32x4_t){0.0f, 0.0f, 0.0f, 0.0f};
            ac20[nt] = __builtin_amdgcn_mfma_f32_16x16x32_bf16(ah0[0], f0, ac20[nt], 0, 0, 0);
            ac21[nt] = __builtin_amdgcn_mfma_f32_16x16x32_bf16(ah1[0], f0, ac21[nt], 0, 0, 0);
            ac20[nt] = __builtin_amdgcn_mfma_f32_16x16x32_bf16(ah0[1], f1, ac20[nt], 0, 0, 0);
            ac21[nt] = __builtin_amdgcn_mfma_f32_16x16x32_bf16(ah1[1], f1, ac21[nt], 0, 0, 0);
        }
        // all h reads issued (in-order DS) -> safe to overwrite with m
        #pragma unroll
        for (int nt = 0; nt < 4; ++nt)
            #pragma unroll
            for (int r = 0; r < 4; ++r) {
                hS[(4 * kq + r) * H_LD + col + 16 * nt]      = (bf16_t)fmaxf(ac20[nt][r] + b2r[nt], 0.0f);
                hS[(16 + 4 * kq + r) * H_LD + col + 16 * nt] = (bf16_t)fmaxf(ac21[nt][r] + b2r[nt], 0.0f);
            }

        // ---- segmented run-merge scatter: lane = col 0..63 over 32 sorted rows ----
        {
            int cur = __builtin_amdgcn_readfirstlane(*(const int*)&hS[66]);  // row0 dst
            float s = 0.0f;
            #pragma unroll 8
            for (int r = 0; r < TW2; ++r) {
                const int d = __builtin_amdgcn_readfirstlane(*(const int*)&hS[r * H_LD + 66]);
                if (d != cur) {
                    atomicAdd(&out_sum[(size_t)cur * ND + lane], s);
                    s = 0.0f; cur = d;
                }
                s += (float)hS[r * H_LD + lane];
            }
            atomicAdd(&out_sum[(size_t)cur * ND + lane], s);
        }
    }
}

// ---------------- K5: finalize out = sum/max(cnt,1) + x ----------------
__global__ void finalize_kernel(const float* __restrict__ x,
                                const int* __restrict__ cnt,
                                float* __restrict__ out)
{
    int i = blockIdx.x * blockDim.x + threadIdx.x;
    int stride = gridDim.x * blockDim.x;
    const int total4 = NODES * ND / 4;
    for (int idx = i; idx < total4; idx += stride) {
        const int n = idx / (ND / 4);
        const float inv = 1.0f / fmaxf((float)cnt[n], 1.0f);
        float4 s = ((const float4*)out)[idx];
        float4 xv = ((const float4*)x)[idx];
        float4 r;
        r.x = s.x * inv + xv.x;
        r.y = s.y * inv + xv.y;
        r.z = s.z * inv + xv.z;
        r.w = s.w * inv + xv.w;
        ((float4*)out)[idx] = r;
    }
}

extern "C" void kernel_launch(void* const* d_in, const int* in_sizes, int n_in,
                              void* d_out, int out_size, void* d_ws, size_t ws_size,
                              hipStream_t stream) {
    const float* x  = (const float*)d_in[0];
    const int*   ei = (const int*)d_in[1];     // int64 in reference -> int32 on device
    const float* ea = (const float*)d_in[2];
    const float* W1 = (const float*)d_in[3];
    const float* b1 = (const float*)d_in[4];
    const float* W2 = (const float*)d_in[5];
    const float* b2 = (const float*)d_in[6];
    float* out = (float*)d_out;

    // d_ws layout (ints): cnt[N] | cursor[N] | pd[2E] | bsum[256]
    int*  cnt    = (int*)d_ws;
    int*  cursor = cnt + NODES;
    int2* pd     = (int2*)(cursor + NODES);
    int*  bsum   = (int*)(pd + NEDGE);

    hipLaunchKernelGGL(zero_kernel, dim3(2048), dim3(256), 0, stream, out, cnt);
    hipLaunchKernelGGL(hist_kernel, dim3(2048), dim3(256), 0, stream, ei, cnt);
    hipLaunchKernelGGL(scan_sum_kernel, dim3(SCAN_NBLK), dim3(SCAN_B), 0, stream, cnt, bsum);
    hipLaunchKernelGGL(scan_top_kernel, dim3(1), dim3(SCAN_B), 0, stream, bsum);
    hipLaunchKernelGGL(scan_fill_kernel, dim3(SCAN_NBLK), dim3(SCAN_B), 0, stream, cnt, bsum, cursor);
    hipLaunchKernelGGL(bucket_kernel, dim3(2048), dim3(256), 0, stream, ei, cursor, pd);
    hipLaunchKernelGGL(edge_mlp_mfma, dim3(1024), dim3(256), 0, stream,
                       x, ea, W1, b1, W2, b2, pd, out);
    hipLaunchKernelGGL(finalize_kernel, dim3(1600), dim3(256), 0, stream, x, cnt, out);
}

// Round 12
// 259.701 us; speedup vs baseline: 1.2676x; 1.2676x over previous
//
#include <hip/hip_runtime.h>

// Problem constants (match reference setup_inputs)
#define NODES 50000
#define NEDGE 1600000
#define ND 64      // NODE_DIM
#define ED 32      // EDGE_DIM
#define HID 64     // HIDDEN
#define IN_DIM 96  // ND + ED

#define TW 16        // edges per wave-private micro-tile
#define MSG_LD 104   // bf16/row: 96+8 pad -> 208 B rows
#define H_LD   72    // bf16/row: 64+8 pad -> 144 B rows (h and m overlay)
#define W1_LD  104   // w1T row stride (bf16): [cn][k] rows 208 B
#define W2_LD  72    // w2T row stride (bf16): 144 B

typedef __bf16 bf16_t;
typedef __bf16 bf16x4_t __attribute__((ext_vector_type(4)));
typedef __bf16 bf16x8_t __attribute__((ext_vector_type(8)));
typedef float  f32x4_t  __attribute__((ext_vector_type(4)));

#define SCAN_B 256
#define SCAN_NBLK ((NODES + SCAN_B - 1) / SCAN_B)   // 196

#define NXCD 8
#define NODES_PER_G ((NODES + NXCD - 1) / NXCD)   // 6250

// ---------------- K0: zero out accumulator + counts ----------------
__global__ void zero_kernel(float* __restrict__ out, int* __restrict__ cnt) {
    int i = blockIdx.x * blockDim.x + threadIdx.x;
    int stride = gridDim.x * blockDim.x;
    const int total = NODES * ND;
    for (int idx = i; idx < total; idx += stride) out[idx] = 0.0f;
    for (int idx = i; idx < NODES; idx += stride) cnt[idx] = 0;
}

// ---------------- K1: histogram of dst ----------------
__global__ void hist_kernel(const int* __restrict__ ei, int* __restrict__ cnt) {
    int i = blockIdx.x * blockDim.x + threadIdx.x;
    int stride = gridDim.x * blockDim.x;
    for (int e = i; e < NEDGE; e += stride)
        atomicAdd(&cnt[ei[NEDGE + e]], 1);
}

// ---------------- K2a: per-block partial sums of cnt ----------------
__global__ void scan_sum_kernel(const int* __restrict__ cnt, int* __restrict__ bsum) {
    __shared__ int sh[SCAN_B];
    const int t = threadIdx.x, b = blockIdx.x;
    const int i = b * SCAN_B + t;
    sh[t] = (i < NODES) ? cnt[i] : 0;
    __syncthreads();
    for (int d = SCAN_B / 2; d > 0; d >>= 1) {
        if (t < d) sh[t] += sh[t + d];
        __syncthreads();
    }
    if (t == 0) bsum[b] = sh[0];
}

// ---------------- K2b: exclusive scan of 196 block sums (1 tiny block) ----------------
__global__ void scan_top_kernel(int* __restrict__ bsum) {
    __shared__ int sh[SCAN_B];
    const int t = threadIdx.x;
    sh[t] = (t < SCAN_NBLK) ? bsum[t] : 0;
    __syncthreads();
    for (int d = 1; d < SCAN_B; d <<= 1) {
        int v = (t >= d) ? sh[t - d] : 0;
        __syncthreads();
        sh[t] += v;
        __syncthreads();
    }
    if (t < SCAN_NBLK) bsum[t] = (t == 0) ? 0 : sh[t - 1];   // exclusive
}

// ---------------- K2c: fill cursor = global exclusive prefix of cnt ----------------
__global__ void scan_fill_kernel(const int* __restrict__ cnt, const int* __restrict__ bsum,
                                 int* __restrict__ cursor) {
    __shared__ int sh[SCAN_B];
    const int t = threadIdx.x, b = blockIdx.x;
    const int i = b * SCAN_B + t;
    int v = (i < NODES) ? cnt[i] : 0;
    sh[t] = v;
    __syncthreads();
    for (int d = 1; d < SCAN_B; d <<= 1) {
        int u = (t >= d) ? sh[t - d] : 0;
        __syncthreads();
        sh[t] += u;
        __syncthreads();
    }
    if (i < NODES) cursor[i] = bsum[b] + sh[t] - v;   // exclusive
}

// ---------------- K3: bucket-scatter, XCD-partitioned by dst range ----------------
__global__ void bucket_kernel(const int* __restrict__ ei, int* __restrict__ cursor,
                              int2* __restrict__ pd) {
    const int g   = blockIdx.x & (NXCD - 1);
    const int bg  = blockIdx.x >> 3;            // block index within group
    const int bpg = gridDim.x >> 3;             // blocks per group
    const int lo  = g * NODES_PER_G;
    const int hi  = min(lo + NODES_PER_G, NODES);
    int i = bg * blockDim.x + threadIdx.x;
    int stride = bpg * blockDim.x;
    for (int e = i; e < NEDGE; e += stride) {
        int d = ei[NEDGE + e];
        if (d >= lo && d < hi) {
            int pos = atomicAdd(&cursor[d], 1);
            pd[pos] = make_int2(e, d);
        }
    }
}

// ---------------- K4: per-edge MLP via bf16 MFMA — wave-private tiles + register prefetch ----------------
// R10 structure (coalesced LDS staging, LDS weights, 1 barrier) + T14 pipeline:
// next tile's pd/x/edge_attr live in registers during current tile's GEMM+scatter.
__global__ __launch_bounds__(256, 4)
void edge_mlp_mfma(const float* __restrict__ x,
                   const float* __restrict__ edge_attr,
                   const float* __restrict__ W1, const float* __restrict__ b1,
                   const float* __restrict__ W2, const float* __restrict__ b2,
                   const int2* __restrict__ pd,
                   float* __restrict__ out_sum)
{
    __shared__ __align__(16) bf16_t w1T[HID * W1_LD];       // [cn][k] 13312 B
    __shared__ __align__(16) bf16_t w2T[ND * W2_LD];        // [cn][k]  9216 B
    __shared__ __align__(16) bf16_t msg_all[4 * TW * MSG_LD]; // per-wave [16][104] 13312 B
    __shared__ int dstw_all[4 * TW];

    const int t    = threadIdx.x;
    const int lane = t & 63;
    const int w    = t >> 6;         // wave id 0..3
    const int col  = lane & 15;      // MFMA col / A-row selector
    const int kq   = lane >> 4;      // 0..3: k-quarter
    const int e    = lane >> 2;      // staging: edge row 0..15
    const int c    = lane & 3;       // staging: 4 lanes per row

    bf16_t* msg  = msg_all + w * TW * MSG_LD;   // [16][MSG_LD]
    bf16_t* hS   = msg;                          // [16][H_LD] overlay (h, then m)
    int*    dstw = dstw_all + w * TW;

    // ---- one-time: transpose W1,W2 into LDS (bf16) ----
    for (int i = t; i < IN_DIM * HID / 4; i += 256) {
        float4 v = ((const float4*)W1)[i];
        int k = i >> 4, j4 = (i & 15) * 4;      // W1[k][j4..j4+3]
        w1T[(j4 + 0) * W1_LD + k] = (bf16_t)v.x;
        w1T[(j4 + 1) * W1_LD + k] = (bf16_t)v.y;
        w1T[(j4 + 2) * W1_LD + k] = (bf16_t)v.z;
        w1T[(j4 + 3) * W1_LD + k] = (bf16_t)v.w;
    }
    for (int i = t; i < HID * ND / 4; i += 256) {
        float4 v = ((const float4*)W2)[i];
        int k = i >> 4, j4 = (i & 15) * 4;
        w2T[(j4 + 0) * W2_LD + k] = (bf16_t)v.x;
        w2T[(j4 + 1) * W2_LD + k] = (bf16_t)v.y;
        w2T[(j4 + 2) * W2_LD + k] = (bf16_t)v.z;
        w2T[(j4 + 3) * W2_LD + k] = (bf16_t)v.w;
    }
    float b1r[4], b2r[4];
    #pragma unroll
    for (int nt = 0; nt < 4; ++nt) {
        b1r[nt] = b1[col + 16 * nt];
        b2r[nt] = b2[col + 16 * nt];
    }
    __syncthreads();   // the only block barrier

    const int ntiles = NEDGE / TW;               // 100000
    const int wid = blockIdx.x * 4 + w;
    const int nw  = gridDim.x * 4;

    // ---- prefetch registers: this lane's share of one tile ----
    float4 xv0, xv1, xv2, xv3;   // x row chunks c, c+4, c+8, c+12
    float4 ev0, ev1;             // ea row chunks c*2, c*2+1
    int    dstv;                 // dstw payload (lane<TW)

    // prologue: load first tile (wid < ntiles always: 4096 waves << 100000 tiles)
    {
        const int eb0 = wid * TW;
        int2 rec = pd[eb0 + e];
        dstv = pd[eb0 + (lane & (TW - 1))].y;
        const float4* xr = (const float4*)(x + (size_t)rec.y * ND);
        const float4* er = (const float4*)(edge_attr + (size_t)rec.x * ED);
        xv0 = xr[c]; xv1 = xr[c + 4]; xv2 = xr[c + 8]; xv3 = xr[c + 12];
        ev0 = er[c * 2]; ev1 = er[c * 2 + 1];
    }

    for (int tile = wid; tile < ntiles; tile += nw) {
        // ---- stage current registers into LDS (coalesced pattern = R10) ----
        if (lane < TW) dstw[lane] = dstv;
        {
            bf16x4_t p;
            p[0] = (bf16_t)xv0.x; p[1] = (bf16_t)xv0.y; p[2] = (bf16_t)xv0.z; p[3] = (bf16_t)xv0.w;
            *(bf16x4_t*)&msg[e * MSG_LD + (c + 0) * 4] = p;
            p[0] = (bf16_t)xv1.x; p[1] = (bf16_t)xv1.y; p[2] = (bf16_t)xv1.z; p[3] = (bf16_t)xv1.w;
            *(bf16x4_t*)&msg[e * MSG_LD + (c + 4) * 4] = p;
            p[0] = (bf16_t)xv2.x; p[1] = (bf16_t)xv2.y; p[2] = (bf16_t)xv2.z; p[3] = (bf16_t)xv2.w;
            *(bf16x4_t*)&msg[e * MSG_LD + (c + 8) * 4] = p;
            p[0] = (bf16_t)xv3.x; p[1] = (bf16_t)xv3.y; p[2] = (bf16_t)xv3.z; p[3] = (bf16_t)xv3.w;
            *(bf16x4_t*)&msg[e * MSG_LD + (c + 12) * 4] = p;
            p[0] = (bf16_t)ev0.x; p[1] = (bf16_t)ev0.y; p[2] = (bf16_t)ev0.z; p[3] = (bf16_t)ev0.w;
            *(bf16x4_t*)&msg[e * MSG_LD + ND + (c * 2 + 0) * 4] = p;
            p[0] = (bf16_t)ev1.x; p[1] = (bf16_t)ev1.y; p[2] = (bf16_t)ev1.z; p[3] = (bf16_t)ev1.w;
            *(bf16x4_t*)&msg[e * MSG_LD + ND + (c * 2 + 1) * 4] = p;
        }

        // ---- issue next tile's loads (fly during GEMM+scatter below) ----
        if (tile + nw < ntiles) {
            const int eb1 = (tile + nw) * TW;
            int2 rec = pd[eb1 + e];
            dstv = pd[eb1 + (lane & (TW - 1))].y;
            const float4* xr = (const float4*)(x + (size_t)rec.y * ND);
            const float4* er = (const float4*)(edge_attr + (size_t)rec.x * ED);
            xv0 = xr[c]; xv1 = xr[c + 4]; xv2 = xr[c + 8]; xv3 = xr[c + 12];
            ev0 = er[c * 2]; ev1 = er[c * 2 + 1];
        }

        // ---- GEMM1: h[0..15][0..63] = relu(msg @ W1 + b1) ----
        const int ab = col * MSG_LD + kq * 8;
        bf16x8_t af0 = *(const bf16x8_t*)&msg[ab + 0 * 32];
        bf16x8_t af1 = *(const bf16x8_t*)&msg[ab + 1 * 32];
        bf16x8_t af2 = *(const bf16x8_t*)&msg[ab + 2 * 32];
        f32x4_t acc[4];
        #pragma unroll
        for (int nt = 0; nt < 4; ++nt) {
            const bf16_t* wrow = &w1T[(col + 16 * nt) * W1_LD + kq * 8];
            bf16x8_t f0 = *(const bf16x8_t*)(wrow + 0 * 32);
            bf16x8_t f1 = *(const bf16x8_t*)(wrow + 1 * 32);
            bf16x8_t f2 = *(const bf16x8_t*)(wrow + 2 * 32);
            acc[nt] = (f32x4_t){0.0f, 0.0f, 0.0f, 0.0f};
            acc[nt] = __builtin_amdgcn_mfma_f32_16x16x32_bf16(af0, f0, acc[nt], 0, 0, 0);
            acc[nt] = __builtin_amdgcn_mfma_f32_16x16x32_bf16(af1, f1, acc[nt], 0, 0, 0);
            acc[nt] = __builtin_amdgcn_mfma_f32_16x16x32_bf16(af2, f2, acc[nt], 0, 0, 0);
        }
        // C/D layout: row = 4*kq + r, col = col + 16*nt
        #pragma unroll
        for (int nt = 0; nt < 4; ++nt)
            #pragma unroll
            for (int r = 0; r < 4; ++r)
                hS[(4 * kq + r) * H_LD + col + 16 * nt] =
                    (bf16_t)fmaxf(acc[nt][r] + b1r[nt], 0.0f);

        // ---- GEMM2: m = relu(h @ W2 + b2); m overwrites h in place ----
        const int hb = col * H_LD + kq * 8;
        bf16x8_t ah0 = *(const bf16x8_t*)&hS[hb + 0 * 32];
        bf16x8_t ah1 = *(const bf16x8_t*)&hS[hb + 1 * 32];
        f32x4_t acc2[4];
        #pragma unroll
        for (int nt = 0; nt < 4; ++nt) {
            const bf16_t* wrow = &w2T[(col + 16 * nt) * W2_LD + kq * 8];
            bf16x8_t f0 = *(const bf16x8_t*)(wrow + 0 * 32);
            bf16x8_t f1 = *(const bf16x8_t*)(wrow + 1 * 32);
            acc2[nt] = (f32x4_t){0.0f, 0.0f, 0.0f, 0.0f};
            acc2[nt] = __builtin_amdgcn_mfma_f32_16x16x32_bf16(ah0, f0, acc2[nt], 0, 0, 0);
            acc2[nt] = __builtin_amdgcn_mfma_f32_16x16x32_bf16(ah1, f1, acc2[nt], 0, 0, 0);
        }
        // LDS ops are in-order per wave -> overlay m-over-h is safe
        #pragma unroll
        for (int nt = 0; nt < 4; ++nt)
            #pragma unroll
            for (int r = 0; r < 4; ++r)
                hS[(4 * kq + r) * H_LD + col + 16 * nt] =
                    (bf16_t)fmaxf(acc2[nt][r] + b2r[nt], 0.0f);

        // ---- segmented run-merge scatter: lane = col 0..63 over 16 sorted rows ----
        {
            int cur = __builtin_amdgcn_readfirstlane(dstw[0]);
            float s = 0.0f;
            #pragma unroll
            for (int r = 0; r < TW; ++r) {
                const int d = __builtin_amdgcn_readfirstlane(dstw[r]);  // uniform -> scalar branch
                if (d != cur) {
                    atomicAdd(&out_sum[(size_t)cur * ND + lane], s);
                    s = 0.0f; cur = d;
                }
                s += (float)hS[r * H_LD + lane];
            }
            atomicAdd(&out_sum[(size_t)cur * ND + lane], s);
        }
    }
}

// ---------------- K5: finalize out = sum/max(cnt,1) + x ----------------
__global__ void finalize_kernel(const float* __restrict__ x,
                                const int* __restrict__ cnt,
                                float* __restrict__ out)
{
    int i = blockIdx.x * blockDim.x + threadIdx.x;
    int stride = gridDim.x * blockDim.x;
    const int total4 = NODES * ND / 4;
    for (int idx = i; idx < total4; idx += stride) {
        const int n = idx / (ND / 4);
        const float inv = 1.0f / fmaxf((float)cnt[n], 1.0f);
        float4 s = ((const float4*)out)[idx];
        float4 xv = ((const float4*)x)[idx];
        float4 r;
        r.x = s.x * inv + xv.x;
        r.y = s.y * inv + xv.y;
        r.z = s.z * inv + xv.z;
        r.w = s.w * inv + xv.w;
        ((float4*)out)[idx] = r;
    }
}

extern "C" void kernel_launch(void* const* d_in, const int* in_sizes, int n_in,
                              void* d_out, int out_size, void* d_ws, size_t ws_size,
                              hipStream_t stream) {
    const float* x  = (const float*)d_in[0];
    const int*   ei = (const int*)d_in[1];     // int64 in reference -> int32 on device
    const float* ea = (const float*)d_in[2];
    const float* W1 = (const float*)d_in[3];
    const float* b1 = (const float*)d_in[4];
    const float* W2 = (const float*)d_in[5];
    const float* b2 = (const float*)d_in[6];
    float* out = (float*)d_out;

    // d_ws layout (ints): cnt[N] | cursor[N] | pd[2E] | bsum[256]
    int*  cnt    = (int*)d_ws;
    int*  cursor = cnt + NODES;
    int2* pd     = (int2*)(cursor + NODES);
    int*  bsum   = (int*)(pd + NEDGE);

    hipLaunchKernelGGL(zero_kernel, dim3(2048), dim3(256), 0, stream, out, cnt);
    hipLaunchKernelGGL(hist_kernel, dim3(2048), dim3(256), 0, stream, ei, cnt);
    hipLaunchKernelGGL(scan_sum_kernel, dim3(SCAN_NBLK), dim3(SCAN_B), 0, stream, cnt, bsum);
    hipLaunchKernelGGL(scan_top_kernel, dim3(1), dim3(SCAN_B), 0, stream, bsum);
    hipLaunchKernelGGL(scan_fill_kernel, dim3(SCAN_NBLK), dim3(SCAN_B), 0, stream, cnt, bsum, cursor);
    hipLaunchKernelGGL(bucket_kernel, dim3(2048), dim3(256), 0, stream, ei, cursor, pd);
    hipLaunchKernelGGL(edge_mlp_mfma, dim3(1024), dim3(256), 0, stream,
                       x, ea, W1, b1, W2, b2, pd, out);
    hipLaunchKernelGGL(finalize_kernel, dim3(1600), dim3(256), 0, stream, x, cnt, out);
}